// Round 5
// baseline (15863.284 us; speedup 1.0000x reference)
//
#include <hip/hip_runtime.h>
#include <hip/hip_fp16.h>
#include <math.h>

#define N_NODES 100000
#define N_EDGES 1600000
#define MAX_ITER 50
#define THRESH 0.01f
#define SCAN_CHUNK 1024
#define NBLK_SCAN 98            // ceil(100000/1024)
#define NB_ITER ((N_EDGES + 255) / 256)   // 6250
#define CHUNK 512               // LDS slots per reduction chunk

// ---------------- ws layout (total 96,801,664 B; harness gives >=103 MB) ---
//   off   : 0           (N+1 ints)        -> pad 400,128
//   cnt   : 400,128     (N ints)          -> 800,128
//   flags : 800,128     (51 + kcnt ints)  -> pad 800,384
//   wc    : 800,384     (295 f32 weights) -> pad 801,664
//   buf0  : 801,664     (N*8 f32 state, stride 8)
//   buf1  : 4,001,664
//   perm  : 7,201,664   (E ints)
//   rowsg : 13,601,664  (E ints, row per CSR slot)
//   rec   : 20,001,664  (E * 48 B: c1[15] fp16 | pad | src i32 | val f32 | pad)
//   bsum  : scratch inside rec region (dead before rec is written)

__device__ __forceinline__ float fast_tanh(float x) {
    float ax = fabsf(x);
    float e = __expf(2.0f * ax);
    float r = 1.0f - 2.0f * __builtin_amdgcn_rcpf(e + 1.0f);
    return copysignf(r, x);
}

__global__ void zero_ints(int* p, int n) {
    int i = blockIdx.x * blockDim.x + threadIdx.x;
    if (i < n) p[i] = 0;
}

__global__ void hist_kernel(const int* __restrict__ rows, int* __restrict__ cnt) {
    int e = blockIdx.x * blockDim.x + threadIdx.x;
    if (e < N_EDGES) atomicAdd(&cnt[rows[e]], 1);
}

__global__ __launch_bounds__(256) void scan1_kernel(const int* __restrict__ cnt,
                                                    int* __restrict__ off,
                                                    int* __restrict__ bsum) {
    __shared__ int sm[256];
    int b = blockIdx.x, t = threadIdx.x;
    int base = b * SCAN_CHUNK + t * 4;
    int v[4];
    int tsum = 0;
#pragma unroll
    for (int j = 0; j < 4; ++j) {
        v[j] = (base + j < N_NODES) ? cnt[base + j] : 0;
        tsum += v[j];
    }
    int val = tsum;
    sm[t] = val;
    __syncthreads();
    for (int d = 1; d < 256; d <<= 1) {
        int x = (t >= d) ? sm[t - d] : 0;
        __syncthreads();
        val += x;
        sm[t] = val;
        __syncthreads();
    }
    int run = val - tsum;
#pragma unroll
    for (int j = 0; j < 4; ++j) {
        if (base + j < N_NODES) off[base + j] = run;
        run += v[j];
    }
    if (t == 255) bsum[b] = val;
}

__global__ __launch_bounds__(128) void scan2_kernel(int* __restrict__ bsum) {
    __shared__ int sm[128];
    int t = threadIdx.x;
    int v = (t < NBLK_SCAN) ? bsum[t] : 0;
    int val = v;
    sm[t] = val;
    __syncthreads();
    for (int d = 1; d < 128; d <<= 1) {
        int x = (t >= d) ? sm[t - d] : 0;
        __syncthreads();
        val += x;
        sm[t] = val;
        __syncthreads();
    }
    if (t < NBLK_SCAN) bsum[t] = val - v;
}

__global__ __launch_bounds__(256) void scan3_kernel(int* __restrict__ off,
                                                    const int* __restrict__ bsum) {
    int b = blockIdx.x, t = threadIdx.x;
    int add = bsum[b];
    int base = b * SCAN_CHUNK + t * 4;
#pragma unroll
    for (int j = 0; j < 4; ++j)
        if (base + j < N_NODES) off[base + j] += add;
    if (b == 0 && t == 0) off[N_NODES] = N_EDGES;
}

__global__ void scatter_perm(const int* __restrict__ rows,
                             const int* __restrict__ off,
                             int* __restrict__ cur,
                             int* __restrict__ perm) {
    int e = blockIdx.x * blockDim.x + threadIdx.x;
    if (e >= N_EDGES) return;
    int r = rows[e];
    int p = off[r] + atomicAdd(&cur[r], 1);
    perm[p] = e;
}

// wc layout: [0..74] W1S[j*5+i]=W1[(8+i)*15+j] | [75..149] W2T[j*15+i]=W2[i*5+j]
//            [150..154] b2 | [160..279] W1F[j*8+i]=W1[i*15+j] | [280..294] b1
__global__ void wprep_kernel(const float* __restrict__ W1, const float* __restrict__ b1,
                             const float* __restrict__ W2, const float* __restrict__ b2,
                             float* __restrict__ wc) {
    int t = threadIdx.x;
    for (int idx = t; idx < 75; idx += 256) { int j = idx / 5, i = idx % 5; wc[idx] = W1[(8 + i) * 15 + j]; }
    for (int idx = t; idx < 75; idx += 256) { int j = idx / 15, i = idx % 15; wc[75 + idx] = W2[i * 5 + j]; }
    for (int idx = t; idx < 5; idx += 256) wc[150 + idx] = b2[idx];
    for (int idx = t; idx < 120; idx += 256) { int j = idx / 8, i = idx % 8; wc[160 + idx] = W1[i * 15 + j]; }
    for (int idx = t; idx < 15; idx += 256) wc[280 + idx] = b1[idx];
}

union RecPack { __half2 h2[8]; uint4 u4[2]; };

// Gather-side record build: sequential writes, iteration-invariant c1 hoisted.
__global__ __launch_bounds__(256) void build_rec(
    const int* __restrict__ perm, const int* __restrict__ rows,
    const int* __restrict__ esrc, const float* __restrict__ avals,
    const float* __restrict__ efeat, const float* __restrict__ wc,
    char* __restrict__ rec, int* __restrict__ rowsg) {
    int p = blockIdx.x * blockDim.x + threadIdx.x;
    if (p >= N_EDGES) return;
    int e = perm[p];
    const float4* fp = (const float4*)(efeat + (size_t)e * 8);
    float4 f0 = fp[0], f1 = fp[1];
    const float* W1F = wc + 160;
    const float* B1 = wc + 280;
    float c[15];
#pragma unroll
    for (int j = 0; j < 15; ++j) {
        float a = B1[j];
        a += f0.x * W1F[j * 8 + 0] + f0.y * W1F[j * 8 + 1] + f0.z * W1F[j * 8 + 2] + f0.w * W1F[j * 8 + 3];
        a += f1.x * W1F[j * 8 + 4] + f1.y * W1F[j * 8 + 5] + f1.z * W1F[j * 8 + 6] + f1.w * W1F[j * 8 + 7];
        c[j] = a;
    }
    RecPack rp;
#pragma unroll
    for (int j = 0; j < 7; ++j) rp.h2[j] = __floats2half2_rn(c[2 * j], c[2 * j + 1]);
    rp.h2[7] = __floats2half2_rn(c[14], 0.f);
    char* dst = rec + (size_t)p * 48;
    ((uint4*)dst)[0] = rp.u4[0];
    ((uint4*)dst)[1] = rp.u4[1];
    *(int2*)(dst + 32) = make_int2(esrc[e], __float_as_int(avals[e]));
    rowsg[p] = rows[e];
}

__global__ void init_state8_kernel(const float* __restrict__ state_init,
                                   const float* __restrict__ old_init,
                                   float* __restrict__ buf0,
                                   int* __restrict__ flags) {
    int n = blockIdx.x * blockDim.x + threadIdx.x;
    if (n >= N_NODES) return;
    float ss = 0.f;
    float s[5];
#pragma unroll
    for (int j = 0; j < 5; ++j) {
        s[j] = state_init[n * 5 + j];
        float d = s[j] - old_init[n * 5 + j];
        ss += d * d;
    }
    ((float4*)(buf0 + (size_t)n * 8))[0] = make_float4(s[0], s[1], s[2], s[3]);
    ((float4*)(buf0 + (size_t)n * 8))[1] = make_float4(s[4], 0.f, 0.f, 0.f);
    int pred = sqrtf(ss + 1e-11f) > THRESH;
    unsigned long long m = __ballot(pred);
    if ((threadIdx.x & 63) == 0 && m) atomicOr(&flags[0], 1);
}

// One kernel per iteration: edge MLP + in-block segmented reduction.
// Block b owns nodes whose CSR run starts in [b*256, (b+1)*256); plain stores only.
__global__ __launch_bounds__(256) void seg_iter_kernel(
    const int* __restrict__ off, const int* __restrict__ rowsg,
    const char* __restrict__ rec,
    const float* __restrict__ sprev, float* __restrict__ snext,
    const float* __restrict__ wc,
    const int* __restrict__ flag_cur, int* __restrict__ flag_next,
    int* __restrict__ kcnt) {
    __shared__ float lv[5][CHUNK];
    __shared__ int lrow[CHUNK];
    __shared__ float cv[5];
    __shared__ int crow;

    int b = blockIdx.x, t = threadIdx.x;
    // node range owned by this block (binary searches on off)
    int target0 = b * 256;
    int lo = 0, hi = N_NODES;
    while (lo < hi) { int mid = (lo + hi) >> 1; if (off[mid] < target0) lo = mid + 1; else hi = mid; }
    int n_lo = lo;
    int n_hi;
    if (b == NB_ITER - 1) {
        n_hi = N_NODES;
    } else {
        int target1 = target0 + 256;
        hi = N_NODES;
        while (lo < hi) { int mid = (lo + hi) >> 1; if (off[mid] < target1) lo = mid + 1; else hi = mid; }
        n_hi = lo;
    }

    if (*flag_cur == 0) {
        int cntn = (n_hi - n_lo) * 8;
        for (int i = t; i < cntn; i += 256)
            snext[(size_t)n_lo * 8 + i] = sprev[(size_t)n_lo * 8 + i];
        return;
    }
    if (b == 0 && t == 0) *kcnt += 1;

    bool pred_any = false;
    // degree-0 nodes: segment_sum gives 0
    for (int i = t; i < n_hi - n_lo; i += 256) {
        int n = n_lo + i;
        if (off[n] == off[n + 1]) {
            float4 s0 = ((const float4*)(sprev + (size_t)n * 8))[0];
            float s4 = sprev[(size_t)n * 8 + 4];
            ((float4*)(snext + (size_t)n * 8))[0] = make_float4(0.f, 0.f, 0.f, 0.f);
            snext[(size_t)n * 8 + 4] = 0.f;
            float ss = s0.x * s0.x + s0.y * s0.y + s0.z * s0.z + s0.w * s0.w + s4 * s4;
            if (sqrtf(ss + 1e-11f) > THRESH) pred_any = true;
        }
    }

    int s_begin = off[n_lo];
    int s_end = (n_hi > n_lo) ? off[n_hi] : s_begin;
    const float* W1S = wc;        // [15][5]
    const float* W2T = wc + 75;   // [5][15]
    const float* B2 = wc + 150;
    if (t == 0) crow = -1;

    for (int cs = s_begin; cs < s_end; cs += CHUNK) {
        int cn = min(CHUNK, s_end - cs);
        // ---- phase 1: per-slot MLP into LDS ----
        for (int i = t; i < cn; i += 256) {
            int p = cs + i;
            const char* rp = rec + (size_t)p * 48;
            RecPack ru;
            ru.u4[0] = ((const uint4*)rp)[0];
            ru.u4[1] = ((const uint4*)rp)[1];
            int2 rc = *(const int2*)(rp + 32);
            int src = rc.x;
            float av = __int_as_float(rc.y);
            float c1[15];
#pragma unroll
            for (int j = 0; j < 7; ++j) {
                float2 f = __half22float2(ru.h2[j]);
                c1[2 * j] = f.x; c1[2 * j + 1] = f.y;
            }
            c1[14] = __half22float2(ru.h2[7]).x;
            float4 s0 = ((const float4*)(sprev + (size_t)src * 8))[0];
            float s4 = sprev[(size_t)src * 8 + 4];
            float h1[15];
#pragma unroll
            for (int j = 0; j < 15; ++j) {
                float a = c1[j];
                a += s0.x * W1S[j * 5 + 0];
                a += s0.y * W1S[j * 5 + 1];
                a += s0.z * W1S[j * 5 + 2];
                a += s0.w * W1S[j * 5 + 3];
                a += s4 * W1S[j * 5 + 4];
                h1[j] = fast_tanh(a);
            }
#pragma unroll
            for (int j = 0; j < 5; ++j) {
                float a = B2[j];
#pragma unroll
                for (int i2 = 0; i2 < 15; ++i2) a += h1[i2] * W2T[j * 15 + i2];
                lv[j][i] = fast_tanh(a) * av;
            }
            lrow[i] = rowsg[p];
        }
        __syncthreads();
        // ---- phase 2: segment tails walk ----
        bool wr_carry = false;
        float cadd0 = 0, cadd1 = 0, cadd2 = 0, cadd3 = 0, cadd4 = 0;
        int myrow = -1;
        for (int i = t; i < cn; i += 256) {
            int r = lrow[i];
            bool is_tail = (i == cn - 1) || (lrow[i + 1] != r);
            if (!is_tail) continue;
            float s0 = lv[0][i], s1 = lv[1][i], s2 = lv[2][i], s3 = lv[3][i], s4v = lv[4][i];
            int k = i - 1;
            while (k >= 0 && lrow[k] == r) {
                s0 += lv[0][k]; s1 += lv[1][k]; s2 += lv[2][k]; s3 += lv[3][k]; s4v += lv[4][k];
                --k;
            }
            if (k < 0 && crow == r) {
                s0 += cv[0]; s1 += cv[1]; s2 += cv[2]; s3 += cv[3]; s4v += cv[4];
            }
            bool incomplete = (i == cn - 1) && (cs + cn < s_end);
            if (incomplete) {
                wr_carry = true; myrow = r;
                cadd0 = s0; cadd1 = s1; cadd2 = s2; cadd3 = s3; cadd4 = s4v;
            } else {
                float4 sp0 = ((const float4*)(sprev + (size_t)r * 8))[0];
                float sp4 = sprev[(size_t)r * 8 + 4];
                float d0 = s0 - sp0.x, d1 = s1 - sp0.y, d2 = s2 - sp0.z;
                float d3 = s3 - sp0.w, d4 = s4v - sp4;
                float ss = d0 * d0 + d1 * d1 + d2 * d2 + d3 * d3 + d4 * d4;
                ((float4*)(snext + (size_t)r * 8))[0] = make_float4(s0, s1, s2, s3);
                snext[(size_t)r * 8 + 4] = s4v;
                if (sqrtf(ss + 1e-11f) > THRESH) pred_any = true;
            }
        }
        __syncthreads();
        if (wr_carry) {
            crow = myrow;
            cv[0] = cadd0; cv[1] = cadd1; cv[2] = cadd2; cv[3] = cadd3; cv[4] = cadd4;
        }
        // next chunk's post-phase1 __syncthreads orders this write before any read
    }
    unsigned long long m = __ballot(pred_any);
    if ((t & 63) == 0 && m) atomicOr(flag_next, 1);
}

__global__ void final8_kernel(const float* __restrict__ state,
                              const float* __restrict__ W3, const float* __restrict__ b3,
                              const float* __restrict__ W4, const float* __restrict__ b4,
                              const int* __restrict__ kcnt,
                              float* __restrict__ out) {
    int n = blockIdx.x * blockDim.x + threadIdx.x;
    if (n == 0) out[(size_t)N_NODES * 7] = (float)(*kcnt);
    if (n >= N_NODES) return;
    float st[5];
    float4 s0 = ((const float4*)(state + (size_t)n * 8))[0];
    st[0] = s0.x; st[1] = s0.y; st[2] = s0.z; st[3] = s0.w;
    st[4] = state[(size_t)n * 8 + 4];
    float o1[10];
#pragma unroll
    for (int j = 0; j < 10; ++j) {
        float a = b3[j];
#pragma unroll
        for (int i = 0; i < 5; ++i) a += st[i] * W3[i * 10 + j];
        o1[j] = tanhf(a);
    }
    float z[7];
    float m = -1e30f;
#pragma unroll
    for (int j = 0; j < 7; ++j) {
        float a = b4[j];
#pragma unroll
        for (int i = 0; i < 10; ++i) a += o1[i] * W4[i * 7 + j];
        z[j] = a;
        m = fmaxf(m, a);
    }
    float s = 0.f;
#pragma unroll
    for (int j = 0; j < 7; ++j) { z[j] = expf(z[j] - m); s += z[j]; }
    float inv = 1.f / s;
#pragma unroll
    for (int j = 0; j < 7; ++j) out[(size_t)n * 7 + j] = z[j] * inv;
}

extern "C" void kernel_launch(void* const* d_in, const int* in_sizes, int n_in,
                              void* d_out, int out_size, void* d_ws, size_t ws_size,
                              hipStream_t stream) {
    const float* edge_feat  = (const float*)d_in[0];
    const int*   edge_src   = (const int*)d_in[1];
    const int*   arc_rows   = (const int*)d_in[2];
    const float* arc_vals   = (const float*)d_in[3];
    const float* state_init = (const float*)d_in[4];
    const float* old_init   = (const float*)d_in[5];
    const float* W1 = (const float*)d_in[6];
    const float* b1 = (const float*)d_in[7];
    const float* W2 = (const float*)d_in[8];
    const float* b2 = (const float*)d_in[9];
    const float* W3 = (const float*)d_in[10];
    const float* b3 = (const float*)d_in[11];
    const float* W4 = (const float*)d_in[12];
    const float* b4 = (const float*)d_in[13];

    char* ws = (char*)d_ws;
    int*   off   = (int*)(ws + 0);
    int*   cnt   = (int*)(ws + 400128);
    int*   flags = (int*)(ws + 800128);
    int*   kcnt  = flags + 51;
    float* wc    = (float*)(ws + 800384);
    float* buf0  = (float*)(ws + 801664);
    float* buf1  = (float*)(ws + 4001664);
    int*   perm  = (int*)(ws + 7201664);
    int*   rowsg = (int*)(ws + 13601664);
    char*  rec   = (char*)(ws + 20001664);
    int*   bsum  = (int*)(ws + 20001664);  // scratch; dead before rec is written

    int nb = (N_NODES + 255) / 256;
    int eb = (N_EDGES + 255) / 256;

    // ---- one-time CSR + record build ----
    hipLaunchKernelGGL(zero_ints, dim3(nb), dim3(256), 0, stream, cnt, N_NODES);
    hipLaunchKernelGGL(zero_ints, dim3(1), dim3(64), 0, stream, flags, 52);
    hipLaunchKernelGGL(hist_kernel, dim3(eb), dim3(256), 0, stream, arc_rows, cnt);
    hipLaunchKernelGGL(scan1_kernel, dim3(NBLK_SCAN), dim3(256), 0, stream, cnt, off, bsum);
    hipLaunchKernelGGL(scan2_kernel, dim3(1), dim3(128), 0, stream, bsum);
    hipLaunchKernelGGL(scan3_kernel, dim3(NBLK_SCAN), dim3(256), 0, stream, off, bsum);
    hipLaunchKernelGGL(zero_ints, dim3(nb), dim3(256), 0, stream, cnt, N_NODES);
    hipLaunchKernelGGL(scatter_perm, dim3(eb), dim3(256), 0, stream, arc_rows, off, cnt, perm);
    hipLaunchKernelGGL(wprep_kernel, dim3(1), dim3(256), 0, stream, W1, b1, W2, b2, wc);
    hipLaunchKernelGGL(build_rec, dim3(eb), dim3(256), 0, stream,
                       perm, arc_rows, edge_src, arc_vals, edge_feat, wc, rec, rowsg);
    hipLaunchKernelGGL(init_state8_kernel, dim3(nb), dim3(256), 0, stream,
                       state_init, old_init, buf0, flags);

    // ---- 50 fused iterations, one kernel each ----
    for (int it = 0; it < MAX_ITER; ++it) {
        const float* sp = (it & 1) ? buf1 : buf0;
        float*       sn = (it & 1) ? buf0 : buf1;
        hipLaunchKernelGGL(seg_iter_kernel, dim3(NB_ITER), dim3(256), 0, stream,
                           off, rowsg, rec, sp, sn, wc,
                           flags + it, flags + it + 1, kcnt);
    }

    // 50 iterations (even) -> state in buf0
    hipLaunchKernelGGL(final8_kernel, dim3(nb), dim3(256), 0, stream,
                       buf0, W3, b3, W4, b4, kcnt, (float*)d_out);
}

// Round 6
// 4159.691 us; speedup vs baseline: 3.8136x; 3.8136x over previous
//
#include <hip/hip_runtime.h>
#include <hip/hip_fp16.h>
#include <math.h>

#define N_NODES 100000
#define N_EDGES 1600000
#define MAX_ITER 50
#define THRESH 0.01f
#define SCAN_CHUNK 1024
#define NBLK_SCAN 98            // ceil(100000/1024)
#define NB_EDGE ((N_EDGES + 255) / 256)   // 6250 blocks; 1.6M = 25000 exact waves

// ---------------- ws layout (total ~96.8 MB) ----------------
//   off   : 0           (N+1 ints)        -> pad 400,128
//   cnt   : 400,128     (N ints)          -> 800,128
//   flags : 800,128     (51 + kcnt ints)  -> pad 800,384
//   wc    : 800,384     (295 f32 weights) -> pad 801,664
//   buf0  : 801,664     (N*8 f32 state, stride 8)
//   buf1  : 4,001,664
//   perm  : 7,201,664   (E ints)
//   rowsg : 13,601,664  (E ints, row per CSR slot)
//   rec   : 20,001,664  (E * 48 B: c1[15] fp16 | pad | src i32 | val f32 | pad)
//   bsum  : scratch inside rec region (dead before rec is written)

__device__ __forceinline__ float fast_tanh(float x) {
    float ax = fabsf(x);
    float e = __expf(2.0f * ax);
    float r = 1.0f - 2.0f * __builtin_amdgcn_rcpf(e + 1.0f);
    return copysignf(r, x);
}

__global__ void zero_ints(int* p, int n) {
    int i = blockIdx.x * blockDim.x + threadIdx.x;
    if (i < n) p[i] = 0;
}

__global__ void zero_floats(float* p, int n) {
    int i = blockIdx.x * blockDim.x + threadIdx.x;
    if (i < n) p[i] = 0.f;
}

__global__ void hist_kernel(const int* __restrict__ rows, int* __restrict__ cnt) {
    int e = blockIdx.x * blockDim.x + threadIdx.x;
    if (e < N_EDGES) atomicAdd(&cnt[rows[e]], 1);
}

__global__ __launch_bounds__(256) void scan1_kernel(const int* __restrict__ cnt,
                                                    int* __restrict__ off,
                                                    int* __restrict__ bsum) {
    __shared__ int sm[256];
    int b = blockIdx.x, t = threadIdx.x;
    int base = b * SCAN_CHUNK + t * 4;
    int v[4];
    int tsum = 0;
#pragma unroll
    for (int j = 0; j < 4; ++j) {
        v[j] = (base + j < N_NODES) ? cnt[base + j] : 0;
        tsum += v[j];
    }
    int val = tsum;
    sm[t] = val;
    __syncthreads();
    for (int d = 1; d < 256; d <<= 1) {
        int x = (t >= d) ? sm[t - d] : 0;
        __syncthreads();
        val += x;
        sm[t] = val;
        __syncthreads();
    }
    int run = val - tsum;
#pragma unroll
    for (int j = 0; j < 4; ++j) {
        if (base + j < N_NODES) off[base + j] = run;
        run += v[j];
    }
    if (t == 255) bsum[b] = val;
}

__global__ __launch_bounds__(128) void scan2_kernel(int* __restrict__ bsum) {
    __shared__ int sm[128];
    int t = threadIdx.x;
    int v = (t < NBLK_SCAN) ? bsum[t] : 0;
    int val = v;
    sm[t] = val;
    __syncthreads();
    for (int d = 1; d < 128; d <<= 1) {
        int x = (t >= d) ? sm[t - d] : 0;
        __syncthreads();
        val += x;
        sm[t] = val;
        __syncthreads();
    }
    if (t < NBLK_SCAN) bsum[t] = val - v;
}

__global__ __launch_bounds__(256) void scan3_kernel(int* __restrict__ off,
                                                    const int* __restrict__ bsum) {
    int b = blockIdx.x, t = threadIdx.x;
    int add = bsum[b];
    int base = b * SCAN_CHUNK + t * 4;
#pragma unroll
    for (int j = 0; j < 4; ++j)
        if (base + j < N_NODES) off[base + j] += add;
    if (b == 0 && t == 0) off[N_NODES] = N_EDGES;
}

__global__ void scatter_perm(const int* __restrict__ rows,
                             const int* __restrict__ off,
                             int* __restrict__ cur,
                             int* __restrict__ perm) {
    int e = blockIdx.x * blockDim.x + threadIdx.x;
    if (e >= N_EDGES) return;
    int r = rows[e];
    int p = off[r] + atomicAdd(&cur[r], 1);
    perm[p] = e;
}

// wc layout: [0..74] W1S[j*5+i]=W1[(8+i)*15+j] | [75..149] W2T[j*15+i]=W2[i*5+j]
//            [150..154] b2 | [160..279] W1F[j*8+i]=W1[i*15+j] | [280..294] b1
__global__ void wprep_kernel(const float* __restrict__ W1, const float* __restrict__ b1,
                             const float* __restrict__ W2, const float* __restrict__ b2,
                             float* __restrict__ wc) {
    int t = threadIdx.x;
    for (int idx = t; idx < 75; idx += 256) { int j = idx / 5, i = idx % 5; wc[idx] = W1[(8 + i) * 15 + j]; }
    for (int idx = t; idx < 75; idx += 256) { int j = idx / 15, i = idx % 15; wc[75 + idx] = W2[i * 5 + j]; }
    for (int idx = t; idx < 5; idx += 256) wc[150 + idx] = b2[idx];
    for (int idx = t; idx < 120; idx += 256) { int j = idx / 8, i = idx % 8; wc[160 + idx] = W1[i * 15 + j]; }
    for (int idx = t; idx < 15; idx += 256) wc[280 + idx] = b1[idx];
}

union RecPack { __half2 h2[8]; uint4 u4[2]; };

// Gather-side record build: sequential writes, iteration-invariant c1 hoisted.
__global__ __launch_bounds__(256) void build_rec(
    const int* __restrict__ perm, const int* __restrict__ rows,
    const int* __restrict__ esrc, const float* __restrict__ avals,
    const float* __restrict__ efeat, const float* __restrict__ wc,
    char* __restrict__ rec, int* __restrict__ rowsg) {
    int p = blockIdx.x * blockDim.x + threadIdx.x;
    if (p >= N_EDGES) return;
    int e = perm[p];
    const float4* fp = (const float4*)(efeat + (size_t)e * 8);
    float4 f0 = fp[0], f1 = fp[1];
    const float* W1F = wc + 160;
    const float* B1 = wc + 280;
    float c[15];
#pragma unroll
    for (int j = 0; j < 15; ++j) {
        float a = B1[j];
        a += f0.x * W1F[j * 8 + 0] + f0.y * W1F[j * 8 + 1] + f0.z * W1F[j * 8 + 2] + f0.w * W1F[j * 8 + 3];
        a += f1.x * W1F[j * 8 + 4] + f1.y * W1F[j * 8 + 5] + f1.z * W1F[j * 8 + 6] + f1.w * W1F[j * 8 + 7];
        c[j] = a;
    }
    RecPack rp;
#pragma unroll
    for (int j = 0; j < 7; ++j) rp.h2[j] = __floats2half2_rn(c[2 * j], c[2 * j + 1]);
    rp.h2[7] = __floats2half2_rn(c[14], 0.f);
    char* dst = rec + (size_t)p * 48;
    ((uint4*)dst)[0] = rp.u4[0];
    ((uint4*)dst)[1] = rp.u4[1];
    *(int2*)(dst + 32) = make_int2(esrc[e], __float_as_int(avals[e]));
    rowsg[p] = rows[e];
}

__global__ void init_state8_kernel(const float* __restrict__ state_init,
                                   const float* __restrict__ old_init,
                                   float* __restrict__ buf0,
                                   int* __restrict__ flags) {
    int n = blockIdx.x * blockDim.x + threadIdx.x;
    if (n >= N_NODES) return;
    float ss = 0.f;
    float s[5];
#pragma unroll
    for (int j = 0; j < 5; ++j) {
        s[j] = state_init[n * 5 + j];
        float d = s[j] - old_init[n * 5 + j];
        ss += d * d;
    }
    ((float4*)(buf0 + (size_t)n * 8))[0] = make_float4(s[0], s[1], s[2], s[3]);
    ((float4*)(buf0 + (size_t)n * 8))[1] = make_float4(s[4], 0.f, 0.f, 0.f);
    int pred = sqrtf(ss + 1e-11f) > THRESH;
    unsigned long long m = __ballot(pred);
    if ((threadIdx.x & 63) == 0 && m) atomicOr(&flags[0], 1);
}

// ---- hot kernel: edge MLP + wave-level segmented scan; snext pre-zeroed ----
__global__ __launch_bounds__(256) void edge_seg_kernel(
    const int* __restrict__ rowsg, const char* __restrict__ rec,
    const float* __restrict__ sprev, float* __restrict__ snext,
    const float* __restrict__ wc, const int* __restrict__ flag_cur) {
    if (*flag_cur == 0) return;
    int p = blockIdx.x * 256 + threadIdx.x;
    int lane = threadIdx.x & 63;
    int wave_start = p - lane;

    const float* W1S = wc;        // [15][5]
    const float* W2T = wc + 75;   // [5][15]
    const float* B2  = wc + 150;

    int r = -1;
    float v0 = 0.f, v1 = 0.f, v2 = 0.f, v3 = 0.f, v4 = 0.f;
    if (p < N_EDGES) {
        r = rowsg[p];
        const char* rp = rec + (size_t)p * 48;
        RecPack ru;
        ru.u4[0] = ((const uint4*)rp)[0];
        ru.u4[1] = ((const uint4*)rp)[1];
        int2 rc = *(const int2*)(rp + 32);
        int src = rc.x;
        float av = __int_as_float(rc.y);
        float c1[15];
#pragma unroll
        for (int j = 0; j < 7; ++j) {
            float2 f = __half22float2(ru.h2[j]);
            c1[2 * j] = f.x; c1[2 * j + 1] = f.y;
        }
        c1[14] = __half22float2(ru.h2[7]).x;
        float4 s0 = ((const float4*)(sprev + (size_t)src * 8))[0];
        float s4 = sprev[(size_t)src * 8 + 4];
        float h1[15];
#pragma unroll
        for (int j = 0; j < 15; ++j) {
            float a = c1[j];
            a += s0.x * W1S[j * 5 + 0];
            a += s0.y * W1S[j * 5 + 1];
            a += s0.z * W1S[j * 5 + 2];
            a += s0.w * W1S[j * 5 + 3];
            a += s4  * W1S[j * 5 + 4];
            h1[j] = fast_tanh(a);
        }
        float o[5];
#pragma unroll
        for (int j = 0; j < 5; ++j) {
            float a = B2[j];
#pragma unroll
            for (int i = 0; i < 15; ++i) a += h1[i] * W2T[j * 15 + i];
            o[j] = fast_tanh(a) * av;
        }
        v0 = o[0]; v1 = o[1]; v2 = o[2]; v3 = o[3]; v4 = o[4];
    }

    // segmented inclusive scan over the wave (rows are non-decreasing)
#pragma unroll
    for (int d = 1; d < 64; d <<= 1) {
        int rr = __shfl_up(r, d, 64);
        float t0 = __shfl_up(v0, d, 64);
        float t1 = __shfl_up(v1, d, 64);
        float t2 = __shfl_up(v2, d, 64);
        float t3 = __shfl_up(v3, d, 64);
        float t4 = __shfl_up(v4, d, 64);
        if (lane >= d && rr == r) { v0 += t0; v1 += t1; v2 += t2; v3 += t3; v4 += t4; }
    }

    int r0  = __shfl(r, 0, 64);
    int rn  = __shfl_down(r, 1, 64);
    // rows adjacent to this wave (for boundary detection)
    int prev_row = -2, next_row = -2;
    if (lane == 0 && wave_start > 0) prev_row = rowsg[wave_start - 1];
    prev_row = __shfl(prev_row, 0, 64);
    if (lane == 63 && wave_start + 64 < N_EDGES) next_row = rowsg[wave_start + 64];
    next_row = __shfl(next_row, 63, 64);

    bool is_tail = (p < N_EDGES) && r >= 0 && ((lane == 63) || (rn != r));
    if (is_tail) {
        bool head_cont = (r == r0) && (prev_row == r);
        bool tail_cont = (lane == 63) && (next_row == r);
        float* dst = snext + (size_t)r * 8;
        if (head_cont || tail_cont) {
            atomicAdd(dst + 0, v0);
            atomicAdd(dst + 1, v1);
            atomicAdd(dst + 2, v2);
            atomicAdd(dst + 3, v3);
            atomicAdd(dst + 4, v4);
        } else {
            ((float4*)dst)[0] = make_float4(v0, v1, v2, v3);
            dst[4] = v4;
        }
    }
}

// Per-node: convergence flag, kcnt, inactive-copy; zeroes sp for next iter.
__global__ void node_pass_kernel(float* __restrict__ sp, float* __restrict__ sn,
                                 const int* __restrict__ flag_cur,
                                 int* __restrict__ flag_next,
                                 int* __restrict__ kcnt) {
    int n = blockIdx.x * blockDim.x + threadIdx.x;
    if (n >= N_NODES) return;
    bool active = (*flag_cur != 0);
    float4 o0 = ((const float4*)(sp + (size_t)n * 8))[0];
    float o4 = sp[(size_t)n * 8 + 4];
    int pred = 0;
    if (active) {
        if (n == 0) *kcnt += 1;
        float4 s0 = ((const float4*)(sn + (size_t)n * 8))[0];
        float s4 = sn[(size_t)n * 8 + 4];
        float d0 = s0.x - o0.x, d1 = s0.y - o0.y, d2 = s0.z - o0.z;
        float d3 = s0.w - o0.w, d4 = s4 - o4;
        float ss = d0 * d0 + d1 * d1 + d2 * d2 + d3 * d3 + d4 * d4;
        pred = sqrtf(ss + 1e-11f) > THRESH;
    } else {
        // converged: carry state forward
        ((float4*)(sn + (size_t)n * 8))[0] = o0;
        sn[(size_t)n * 8 + 4] = o4;
    }
    // zero sp: it becomes snext (accumulator target) of the next iteration
    ((float4*)(sp + (size_t)n * 8))[0] = make_float4(0.f, 0.f, 0.f, 0.f);
    sp[(size_t)n * 8 + 4] = 0.f;
    unsigned long long m = __ballot(pred);
    if ((threadIdx.x & 63) == 0 && m) atomicOr(flag_next, 1);
}

__global__ void final8_kernel(const float* __restrict__ state,
                              const float* __restrict__ W3, const float* __restrict__ b3,
                              const float* __restrict__ W4, const float* __restrict__ b4,
                              const int* __restrict__ kcnt,
                              float* __restrict__ out) {
    int n = blockIdx.x * blockDim.x + threadIdx.x;
    if (n == 0) out[(size_t)N_NODES * 7] = (float)(*kcnt);
    if (n >= N_NODES) return;
    float st[5];
    float4 s0 = ((const float4*)(state + (size_t)n * 8))[0];
    st[0] = s0.x; st[1] = s0.y; st[2] = s0.z; st[3] = s0.w;
    st[4] = state[(size_t)n * 8 + 4];
    float o1[10];
#pragma unroll
    for (int j = 0; j < 10; ++j) {
        float a = b3[j];
#pragma unroll
        for (int i = 0; i < 5; ++i) a += st[i] * W3[i * 10 + j];
        o1[j] = tanhf(a);
    }
    float z[7];
    float m = -1e30f;
#pragma unroll
    for (int j = 0; j < 7; ++j) {
        float a = b4[j];
#pragma unroll
        for (int i = 0; i < 10; ++i) a += o1[i] * W4[i * 7 + j];
        z[j] = a;
        m = fmaxf(m, a);
    }
    float s = 0.f;
#pragma unroll
    for (int j = 0; j < 7; ++j) { z[j] = expf(z[j] - m); s += z[j]; }
    float inv = 1.f / s;
#pragma unroll
    for (int j = 0; j < 7; ++j) out[(size_t)n * 7 + j] = z[j] * inv;
}

extern "C" void kernel_launch(void* const* d_in, const int* in_sizes, int n_in,
                              void* d_out, int out_size, void* d_ws, size_t ws_size,
                              hipStream_t stream) {
    const float* edge_feat  = (const float*)d_in[0];
    const int*   edge_src   = (const int*)d_in[1];
    const int*   arc_rows   = (const int*)d_in[2];
    const float* arc_vals   = (const float*)d_in[3];
    const float* state_init = (const float*)d_in[4];
    const float* old_init   = (const float*)d_in[5];
    const float* W1 = (const float*)d_in[6];
    const float* b1 = (const float*)d_in[7];
    const float* W2 = (const float*)d_in[8];
    const float* b2 = (const float*)d_in[9];
    const float* W3 = (const float*)d_in[10];
    const float* b3 = (const float*)d_in[11];
    const float* W4 = (const float*)d_in[12];
    const float* b4 = (const float*)d_in[13];

    char* ws = (char*)d_ws;
    int*   off   = (int*)(ws + 0);
    int*   cnt   = (int*)(ws + 400128);
    int*   flags = (int*)(ws + 800128);
    int*   kcnt  = flags + 51;
    float* wc    = (float*)(ws + 800384);
    float* buf0  = (float*)(ws + 801664);
    float* buf1  = (float*)(ws + 4001664);
    int*   perm  = (int*)(ws + 7201664);
    int*   rowsg = (int*)(ws + 13601664);
    char*  rec   = (char*)(ws + 20001664);
    int*   bsum  = (int*)(ws + 20001664);  // scratch; dead before rec is written

    int nb = (N_NODES + 255) / 256;
    int eb = NB_EDGE;

    // ---- one-time CSR + record build ----
    hipLaunchKernelGGL(zero_ints, dim3(nb), dim3(256), 0, stream, cnt, N_NODES);
    hipLaunchKernelGGL(zero_ints, dim3(1), dim3(64), 0, stream, flags, 52);
    hipLaunchKernelGGL(hist_kernel, dim3(eb), dim3(256), 0, stream, arc_rows, cnt);
    hipLaunchKernelGGL(scan1_kernel, dim3(NBLK_SCAN), dim3(256), 0, stream, cnt, off, bsum);
    hipLaunchKernelGGL(scan2_kernel, dim3(1), dim3(128), 0, stream, bsum);
    hipLaunchKernelGGL(scan3_kernel, dim3(NBLK_SCAN), dim3(256), 0, stream, off, bsum);
    hipLaunchKernelGGL(zero_ints, dim3(nb), dim3(256), 0, stream, cnt, N_NODES);
    hipLaunchKernelGGL(scatter_perm, dim3(eb), dim3(256), 0, stream, arc_rows, off, cnt, perm);
    hipLaunchKernelGGL(wprep_kernel, dim3(1), dim3(256), 0, stream, W1, b1, W2, b2, wc);
    hipLaunchKernelGGL(build_rec, dim3(eb), dim3(256), 0, stream,
                       perm, arc_rows, edge_src, arc_vals, edge_feat, wc, rec, rowsg);
    hipLaunchKernelGGL(init_state8_kernel, dim3(nb), dim3(256), 0, stream,
                       state_init, old_init, buf0, flags);
    // buf1 is iteration 0's accumulator target: zero it
    hipLaunchKernelGGL(zero_floats, dim3((N_NODES * 8 + 255) / 256), dim3(256), 0, stream,
                       buf1, N_NODES * 8);

    // ---- 50 iterations: edge_seg (accumulate into pre-zeroed sn) + node_pass ----
    for (int it = 0; it < MAX_ITER; ++it) {
        float* sp = (it & 1) ? buf1 : buf0;
        float* sn = (it & 1) ? buf0 : buf1;
        hipLaunchKernelGGL(edge_seg_kernel, dim3(eb), dim3(256), 0, stream,
                           rowsg, rec, sp, sn, wc, flags + it);
        hipLaunchKernelGGL(node_pass_kernel, dim3(nb), dim3(256), 0, stream,
                           sp, sn, flags + it, flags + it + 1, kcnt);
    }

    // iter 49: sn = buf0 -> final state in buf0
    hipLaunchKernelGGL(final8_kernel, dim3(nb), dim3(256), 0, stream,
                       buf0, W3, b3, W4, b4, kcnt, (float*)d_out);
}

// Round 7
// 3429.572 us; speedup vs baseline: 4.6254x; 1.2129x over previous
//
#include <hip/hip_runtime.h>
#include <hip/hip_fp16.h>
#include <math.h>

#define N_NODES 100000
#define N_EDGES 1600000
#define MAX_ITER 50
#define THRESH 0.01f
#define SCAN_CHUNK 1024
#define NBLK_SCAN 98            // ceil(100000/1024)
#define NB_EDGE ((N_EDGES + 255) / 256)
#define WAVES_TOTAL 3125        // 1.6M / 512 slots per wave
#define BLK_PIPE 782            // ceil(3125*64/256)

// ---------------- ws layout (total 84 MB; harness provides >=103 MB) ------
//   off   : 0           (N+1 ints)        -> pad 400,128
//   cnt   : 400,128     (N ints)          -> 800,128
//   flags : 800,128     (51 + kcnt ints)  -> pad 800,384
//   wc    : 800,384     (295 f32 weights) -> pad 801,664
//   buf0  : 801,664     (N*8 f32 state, stride 8)
//   buf1  : 4,001,664
//   perm  : 7,201,664   (E ints)
//   rowsg : 13,601,664  (E ints, row per CSR slot)
//   c1h   : 20,001,664  (E * 32 B: hoisted W1·feat+b1 as 15 fp16)  [bsum scratch]
//   sv    : 71,201,664  (E int2: src, arc_val bits)

__device__ __forceinline__ float fast_tanh(float x) {
    float ax = fabsf(x);
    float e = __expf(2.0f * ax);
    float r = 1.0f - 2.0f * __builtin_amdgcn_rcpf(e + 1.0f);
    return copysignf(r, x);
}

__global__ void zero_ints(int* p, int n) {
    int i = blockIdx.x * blockDim.x + threadIdx.x;
    if (i < n) p[i] = 0;
}

__global__ void zero_floats(float* p, int n) {
    int i = blockIdx.x * blockDim.x + threadIdx.x;
    if (i < n) p[i] = 0.f;
}

__global__ void hist_kernel(const int* __restrict__ rows, int* __restrict__ cnt) {
    int e = blockIdx.x * blockDim.x + threadIdx.x;
    if (e < N_EDGES) atomicAdd(&cnt[rows[e]], 1);
}

__global__ __launch_bounds__(256) void scan1_kernel(const int* __restrict__ cnt,
                                                    int* __restrict__ off,
                                                    int* __restrict__ bsum) {
    __shared__ int sm[256];
    int b = blockIdx.x, t = threadIdx.x;
    int base = b * SCAN_CHUNK + t * 4;
    int v[4];
    int tsum = 0;
#pragma unroll
    for (int j = 0; j < 4; ++j) {
        v[j] = (base + j < N_NODES) ? cnt[base + j] : 0;
        tsum += v[j];
    }
    int val = tsum;
    sm[t] = val;
    __syncthreads();
    for (int d = 1; d < 256; d <<= 1) {
        int x = (t >= d) ? sm[t - d] : 0;
        __syncthreads();
        val += x;
        sm[t] = val;
        __syncthreads();
    }
    int run = val - tsum;
#pragma unroll
    for (int j = 0; j < 4; ++j) {
        if (base + j < N_NODES) off[base + j] = run;
        run += v[j];
    }
    if (t == 255) bsum[b] = val;
}

__global__ __launch_bounds__(128) void scan2_kernel(int* __restrict__ bsum) {
    __shared__ int sm[128];
    int t = threadIdx.x;
    int v = (t < NBLK_SCAN) ? bsum[t] : 0;
    int val = v;
    sm[t] = val;
    __syncthreads();
    for (int d = 1; d < 128; d <<= 1) {
        int x = (t >= d) ? sm[t - d] : 0;
        __syncthreads();
        val += x;
        sm[t] = val;
        __syncthreads();
    }
    if (t < NBLK_SCAN) bsum[t] = val - v;
}

__global__ __launch_bounds__(256) void scan3_kernel(int* __restrict__ off,
                                                    const int* __restrict__ bsum) {
    int b = blockIdx.x, t = threadIdx.x;
    int add = bsum[b];
    int base = b * SCAN_CHUNK + t * 4;
#pragma unroll
    for (int j = 0; j < 4; ++j)
        if (base + j < N_NODES) off[base + j] += add;
    if (b == 0 && t == 0) off[N_NODES] = N_EDGES;
}

__global__ void scatter_perm(const int* __restrict__ rows,
                             const int* __restrict__ off,
                             int* __restrict__ cur,
                             int* __restrict__ perm) {
    int e = blockIdx.x * blockDim.x + threadIdx.x;
    if (e >= N_EDGES) return;
    int r = rows[e];
    int p = off[r] + atomicAdd(&cur[r], 1);
    perm[p] = e;
}

// wc layout: [0..74] W1S[j*5+i]=W1[(8+i)*15+j] | [75..149] W2T[j*15+i]=W2[i*5+j]
//            [150..154] b2 | [160..279] W1F[j*8+i]=W1[i*15+j] | [280..294] b1
__global__ void wprep_kernel(const float* __restrict__ W1, const float* __restrict__ b1,
                             const float* __restrict__ W2, const float* __restrict__ b2,
                             float* __restrict__ wc) {
    int t = threadIdx.x;
    for (int idx = t; idx < 75; idx += 256) { int j = idx / 5, i = idx % 5; wc[idx] = W1[(8 + i) * 15 + j]; }
    for (int idx = t; idx < 75; idx += 256) { int j = idx / 15, i = idx % 15; wc[75 + idx] = W2[i * 5 + j]; }
    for (int idx = t; idx < 5; idx += 256) wc[150 + idx] = b2[idx];
    for (int idx = t; idx < 120; idx += 256) { int j = idx / 8, i = idx % 8; wc[160 + idx] = W1[i * 15 + j]; }
    for (int idx = t; idx < 15; idx += 256) wc[280 + idx] = b1[idx];
}

union RecPack { __half2 h2[8]; uint4 u4[2]; };
union U4H { uint4 u; __half2 h[4]; };

// Gather-side build: hoist W1·feat+b1 into fp16 planes; SoA split.
__global__ __launch_bounds__(256) void build_rec(
    const int* __restrict__ perm, const int* __restrict__ rows,
    const int* __restrict__ esrc, const float* __restrict__ avals,
    const float* __restrict__ efeat, const float* __restrict__ wc,
    uint4* __restrict__ c1h, int2* __restrict__ sv, int* __restrict__ rowsg) {
    int p = blockIdx.x * blockDim.x + threadIdx.x;
    if (p >= N_EDGES) return;
    int e = perm[p];
    const float4* fp = (const float4*)(efeat + (size_t)e * 8);
    float4 f0 = fp[0], f1 = fp[1];
    const float* W1F = wc + 160;
    const float* B1 = wc + 280;
    float c[15];
#pragma unroll
    for (int j = 0; j < 15; ++j) {
        float a = B1[j];
        a += f0.x * W1F[j * 8 + 0] + f0.y * W1F[j * 8 + 1] + f0.z * W1F[j * 8 + 2] + f0.w * W1F[j * 8 + 3];
        a += f1.x * W1F[j * 8 + 4] + f1.y * W1F[j * 8 + 5] + f1.z * W1F[j * 8 + 6] + f1.w * W1F[j * 8 + 7];
        c[j] = a;
    }
    RecPack rp;
#pragma unroll
    for (int j = 0; j < 7; ++j) rp.h2[j] = __floats2half2_rn(c[2 * j], c[2 * j + 1]);
    rp.h2[7] = __floats2half2_rn(c[14], 0.f);
    c1h[2 * p] = rp.u4[0];
    c1h[2 * p + 1] = rp.u4[1];
    sv[p] = make_int2(esrc[e], __float_as_int(avals[e]));
    rowsg[p] = rows[e];
}

__global__ void init_state8_kernel(const float* __restrict__ state_init,
                                   const float* __restrict__ old_init,
                                   float* __restrict__ buf0,
                                   int* __restrict__ flags) {
    int n = blockIdx.x * blockDim.x + threadIdx.x;
    if (n >= N_NODES) return;
    float ss = 0.f;
    float s[5];
#pragma unroll
    for (int j = 0; j < 5; ++j) {
        s[j] = state_init[n * 5 + j];
        float d = s[j] - old_init[n * 5 + j];
        ss += d * d;
    }
    ((float4*)(buf0 + (size_t)n * 8))[0] = make_float4(s[0], s[1], s[2], s[3]);
    ((float4*)(buf0 + (size_t)n * 8))[1] = make_float4(s[4], 0.f, 0.f, 0.f);
    int pred = sqrtf(ss + 1e-11f) > THRESH;
    unsigned long long m = __ballot(pred);
    if ((threadIdx.x & 63) == 0 && m) atomicOr(&flags[0], 1);
}

// ---- hot kernel: persistent waves, 512 slots/wave, register prefetch,
//      wave segmented scan with in-register carry across 8 groups ----
__global__ __launch_bounds__(256) void edge_pipe_kernel(
    const int* __restrict__ rowsg, const uint4* __restrict__ c1h,
    const int2* __restrict__ sv,
    const float* __restrict__ sprev, float* __restrict__ snext,
    const float* __restrict__ wc, const int* __restrict__ flag_cur) {
    if (*flag_cur == 0) return;
    int gtid = blockIdx.x * 256 + threadIdx.x;
    int wid = gtid >> 6;
    int lane = threadIdx.x & 63;
    if (wid >= WAVES_TOTAL) return;
    int base = wid * 512;

    int head_prev = (wid > 0) ? rowsg[base - 1] : -2;
    int tail_next = (wid < WAVES_TOTAL - 1) ? rowsg[base + 512] : -2;

    const float* W1S = wc;        // [15][5]
    const float* W2T = wc + 75;   // [5][15]
    const float* B2  = wc + 150;

    int carry_row = -1;
    bool carry_head = false;
    float cv0 = 0, cv1 = 0, cv2 = 0, cv3 = 0, cv4 = 0;

    // preload group 0
    int p0 = base + lane;
    uint4 a0 = c1h[2 * p0];
    uint4 a1 = c1h[2 * p0 + 1];
    int2 svv = sv[p0];
    int rr = rowsg[p0];

    for (int k = 0; k < 8; ++k) {
        uint4 b0 = a0, b1 = a1;
        int2 s = svv;
        int r = rr;
        if (k < 7) {
            int np = base + (k + 1) * 64 + lane;
            a0 = c1h[2 * np];
            a1 = c1h[2 * np + 1];
            svv = sv[np];
            rr = rowsg[np];
        }
        // state gather (depends only on small sv load)
        float4 st0 = ((const float4*)(sprev + (size_t)s.x * 8))[0];
        float st4 = sprev[(size_t)s.x * 8 + 4];
        float av = __int_as_float(s.y);
        // unpack c1
        U4H ua, ub;
        ua.u = b0; ub.u = b1;
        float c1[15];
#pragma unroll
        for (int j = 0; j < 4; ++j) {
            float2 f = __half22float2(ua.h[j]);
            c1[2 * j] = f.x; c1[2 * j + 1] = f.y;
        }
#pragma unroll
        for (int j = 0; j < 3; ++j) {
            float2 f = __half22float2(ub.h[j]);
            c1[8 + 2 * j] = f.x; c1[9 + 2 * j] = f.y;
        }
        c1[14] = __half22float2(ub.h[3]).x;
        // MLP
        float h1[15];
#pragma unroll
        for (int j = 0; j < 15; ++j) {
            float a = c1[j];
            a += st0.x * W1S[j * 5 + 0];
            a += st0.y * W1S[j * 5 + 1];
            a += st0.z * W1S[j * 5 + 2];
            a += st0.w * W1S[j * 5 + 3];
            a += st4  * W1S[j * 5 + 4];
            h1[j] = fast_tanh(a);
        }
        float v0, v1, v2, v3, v4;
        {
            float o[5];
#pragma unroll
            for (int j = 0; j < 5; ++j) {
                float a = B2[j];
#pragma unroll
                for (int i = 0; i < 15; ++i) a += h1[i] * W2T[j * 15 + i];
                o[j] = fast_tanh(a) * av;
            }
            v0 = o[0]; v1 = o[1]; v2 = o[2]; v3 = o[3]; v4 = o[4];
        }
        // wave segmented inclusive scan (rows non-decreasing)
#pragma unroll
        for (int d = 1; d < 64; d <<= 1) {
            int pr = __shfl_up(r, d, 64);
            float t0 = __shfl_up(v0, d, 64);
            float t1 = __shfl_up(v1, d, 64);
            float t2 = __shfl_up(v2, d, 64);
            float t3 = __shfl_up(v3, d, 64);
            float t4 = __shfl_up(v4, d, 64);
            if (lane >= d && pr == r) { v0 += t0; v1 += t1; v2 += t2; v3 += t3; v4 += t4; }
        }
        int rn = __shfl_down(r, 1, 64);
        int r_next_first = (k < 7) ? __shfl(rr, 0, 64) : -3;

        bool is_tail = (lane == 63) || (rn != r);
        float w0 = v0, w1 = v1, w2 = v2, w3 = v3, w4 = v4;
        if (is_tail && r == carry_row) { w0 += cv0; w1 += cv1; w2 += cv2; w3 += cv3; w4 += cv4; }
        bool rh = (r == carry_row && carry_head) || (k == 0 && head_prev == r);
        bool cont = is_tail && (lane == 63) && (k < 7) && (r == r_next_first);
        if (is_tail && !cont) {
            bool wec = (lane == 63) && (k == 7) && (r == tail_next);
            float* dst = snext + (size_t)r * 8;
            if (rh || wec) {
                atomicAdd(dst + 0, w0);
                atomicAdd(dst + 1, w1);
                atomicAdd(dst + 2, w2);
                atomicAdd(dst + 3, w3);
                atomicAdd(dst + 4, w4);
            } else {
                ((float4*)dst)[0] = make_float4(w0, w1, w2, w3);
                dst[4] = w4;
            }
        }
        // broadcast new carry from lane 63
        int cont63 = __shfl((int)cont, 63, 64);
        int cr63 = __shfl(r, 63, 64);
        int ch63 = __shfl((int)rh, 63, 64);
        float nc0 = __shfl(w0, 63, 64);
        float nc1 = __shfl(w1, 63, 64);
        float nc2 = __shfl(w2, 63, 64);
        float nc3 = __shfl(w3, 63, 64);
        float nc4 = __shfl(w4, 63, 64);
        carry_row = cont63 ? cr63 : -1;
        carry_head = cont63 && ch63;
        cv0 = nc0; cv1 = nc1; cv2 = nc2; cv3 = nc3; cv4 = nc4;
    }
}

// Per-node: convergence flag, kcnt, inactive-copy; zeroes sp for next iter.
__global__ void node_pass_kernel(float* __restrict__ sp, float* __restrict__ sn,
                                 const int* __restrict__ flag_cur,
                                 int* __restrict__ flag_next,
                                 int* __restrict__ kcnt) {
    int n = blockIdx.x * blockDim.x + threadIdx.x;
    if (n >= N_NODES) return;
    bool active = (*flag_cur != 0);
    float4 o0 = ((const float4*)(sp + (size_t)n * 8))[0];
    float o4 = sp[(size_t)n * 8 + 4];
    int pred = 0;
    if (active) {
        if (n == 0) *kcnt += 1;
        float4 s0 = ((const float4*)(sn + (size_t)n * 8))[0];
        float s4 = sn[(size_t)n * 8 + 4];
        float d0 = s0.x - o0.x, d1 = s0.y - o0.y, d2 = s0.z - o0.z;
        float d3 = s0.w - o0.w, d4 = s4 - o4;
        float ss = d0 * d0 + d1 * d1 + d2 * d2 + d3 * d3 + d4 * d4;
        pred = sqrtf(ss + 1e-11f) > THRESH;
    } else {
        ((float4*)(sn + (size_t)n * 8))[0] = o0;
        sn[(size_t)n * 8 + 4] = o4;
    }
    ((float4*)(sp + (size_t)n * 8))[0] = make_float4(0.f, 0.f, 0.f, 0.f);
    sp[(size_t)n * 8 + 4] = 0.f;
    unsigned long long m = __ballot(pred);
    if ((threadIdx.x & 63) == 0 && m) atomicOr(flag_next, 1);
}

__global__ void final8_kernel(const float* __restrict__ state,
                              const float* __restrict__ W3, const float* __restrict__ b3,
                              const float* __restrict__ W4, const float* __restrict__ b4,
                              const int* __restrict__ kcnt,
                              float* __restrict__ out) {
    int n = blockIdx.x * blockDim.x + threadIdx.x;
    if (n == 0) out[(size_t)N_NODES * 7] = (float)(*kcnt);
    if (n >= N_NODES) return;
    float st[5];
    float4 s0 = ((const float4*)(state + (size_t)n * 8))[0];
    st[0] = s0.x; st[1] = s0.y; st[2] = s0.z; st[3] = s0.w;
    st[4] = state[(size_t)n * 8 + 4];
    float o1[10];
#pragma unroll
    for (int j = 0; j < 10; ++j) {
        float a = b3[j];
#pragma unroll
        for (int i = 0; i < 5; ++i) a += st[i] * W3[i * 10 + j];
        o1[j] = tanhf(a);
    }
    float z[7];
    float m = -1e30f;
#pragma unroll
    for (int j = 0; j < 7; ++j) {
        float a = b4[j];
#pragma unroll
        for (int i = 0; i < 10; ++i) a += o1[i] * W4[i * 7 + j];
        z[j] = a;
        m = fmaxf(m, a);
    }
    float s = 0.f;
#pragma unroll
    for (int j = 0; j < 7; ++j) { z[j] = expf(z[j] - m); s += z[j]; }
    float inv = 1.f / s;
#pragma unroll
    for (int j = 0; j < 7; ++j) out[(size_t)n * 7 + j] = z[j] * inv;
}

extern "C" void kernel_launch(void* const* d_in, const int* in_sizes, int n_in,
                              void* d_out, int out_size, void* d_ws, size_t ws_size,
                              hipStream_t stream) {
    const float* edge_feat  = (const float*)d_in[0];
    const int*   edge_src   = (const int*)d_in[1];
    const int*   arc_rows   = (const int*)d_in[2];
    const float* arc_vals   = (const float*)d_in[3];
    const float* state_init = (const float*)d_in[4];
    const float* old_init   = (const float*)d_in[5];
    const float* W1 = (const float*)d_in[6];
    const float* b1 = (const float*)d_in[7];
    const float* W2 = (const float*)d_in[8];
    const float* b2 = (const float*)d_in[9];
    const float* W3 = (const float*)d_in[10];
    const float* b3 = (const float*)d_in[11];
    const float* W4 = (const float*)d_in[12];
    const float* b4 = (const float*)d_in[13];

    char* ws = (char*)d_ws;
    int*   off   = (int*)(ws + 0);
    int*   cnt   = (int*)(ws + 400128);
    int*   flags = (int*)(ws + 800128);
    int*   kcnt  = flags + 51;
    float* wc    = (float*)(ws + 800384);
    float* buf0  = (float*)(ws + 801664);
    float* buf1  = (float*)(ws + 4001664);
    int*   perm  = (int*)(ws + 7201664);
    int*   rowsg = (int*)(ws + 13601664);
    uint4* c1h   = (uint4*)(ws + 20001664);
    int2*  sv    = (int2*)(ws + 71201664);
    int*   bsum  = (int*)(ws + 20001664);  // scratch; dead before c1h written

    int nb = (N_NODES + 255) / 256;
    int eb = NB_EDGE;

    // ---- one-time CSR + record build ----
    hipLaunchKernelGGL(zero_ints, dim3(nb), dim3(256), 0, stream, cnt, N_NODES);
    hipLaunchKernelGGL(zero_ints, dim3(1), dim3(64), 0, stream, flags, 52);
    hipLaunchKernelGGL(hist_kernel, dim3(eb), dim3(256), 0, stream, arc_rows, cnt);
    hipLaunchKernelGGL(scan1_kernel, dim3(NBLK_SCAN), dim3(256), 0, stream, cnt, off, bsum);
    hipLaunchKernelGGL(scan2_kernel, dim3(1), dim3(128), 0, stream, bsum);
    hipLaunchKernelGGL(scan3_kernel, dim3(NBLK_SCAN), dim3(256), 0, stream, off, bsum);
    hipLaunchKernelGGL(zero_ints, dim3(nb), dim3(256), 0, stream, cnt, N_NODES);
    hipLaunchKernelGGL(scatter_perm, dim3(eb), dim3(256), 0, stream, arc_rows, off, cnt, perm);
    hipLaunchKernelGGL(wprep_kernel, dim3(1), dim3(256), 0, stream, W1, b1, W2, b2, wc);
    hipLaunchKernelGGL(build_rec, dim3(eb), dim3(256), 0, stream,
                       perm, arc_rows, edge_src, arc_vals, edge_feat, wc, c1h, sv, rowsg);
    hipLaunchKernelGGL(init_state8_kernel, dim3(nb), dim3(256), 0, stream,
                       state_init, old_init, buf0, flags);
    hipLaunchKernelGGL(zero_floats, dim3((N_NODES * 8 + 255) / 256), dim3(256), 0, stream,
                       buf1, N_NODES * 8);

    // ---- 50 iterations: edge_pipe (accumulate into pre-zeroed sn) + node_pass ----
    for (int it = 0; it < MAX_ITER; ++it) {
        float* sp = (it & 1) ? buf1 : buf0;
        float* sn = (it & 1) ? buf0 : buf1;
        hipLaunchKernelGGL(edge_pipe_kernel, dim3(BLK_PIPE), dim3(256), 0, stream,
                           rowsg, c1h, sv, sp, sn, wc, flags + it);
        hipLaunchKernelGGL(node_pass_kernel, dim3(nb), dim3(256), 0, stream,
                           sp, sn, flags + it, flags + it + 1, kcnt);
    }

    hipLaunchKernelGGL(final8_kernel, dim3(nb), dim3(256), 0, stream,
                       buf0, W3, b3, W4, b4, kcnt, (float*)d_out);
}

// Round 8
// 3161.291 us; speedup vs baseline: 5.0180x; 1.0849x over previous
//
#include <hip/hip_runtime.h>
#include <hip/hip_fp16.h>
#include <math.h>

#define N_NODES 100000
#define N_EDGES 1600000
#define MAX_ITER 50
#define THRESH 0.01f
#define SCAN_CHUNK 1024
#define NBLK_SCAN 98            // ceil(100000/1024)
#define NB_EDGE ((N_EDGES + 255) / 256)
#define SLOTS_W 320             // slots per wave
#define GROUPS 5                // 5 groups of 64
#define WAVES_TOTAL 5000        // 1.6M / 320
#define BLK_PIPE 1250           // 5000 waves / 4 per block

// ---------------- ws layout (total 77.6 MB; harness provides >=103 MB) ----
//   off   : 0           (N+1 ints)        -> pad 400,128
//   cnt   : 400,128     (N ints)          -> 800,128
//   flags : 800,128     (51 + kcnt ints)  -> pad 800,384
//   wc    : 800,384     (295 f32 weights) -> pad 801,664
//   buf0  : 801,664     (N*8 f32 state, stride 8)
//   buf1  : 4,001,664
//   rowsg : 7,201,664   (E ints, row per CSR slot)
//   sv    : 13,601,664  (E int2: src, arc_val bits)
//   c1h   : 26,401,664  (E * 32 B: hoisted W1·feat+b1 as 15 fp16) [bsum scratch]

__device__ __forceinline__ float fast_tanh(float x) {
    float ax = fabsf(x);
    float e = __expf(2.0f * ax);
    float r = 1.0f - 2.0f * __builtin_amdgcn_rcpf(e + 1.0f);
    return copysignf(r, x);
}

__global__ void zero_ints(int* p, int n) {
    int i = blockIdx.x * blockDim.x + threadIdx.x;
    if (i < n) p[i] = 0;
}

__global__ void zero_floats(float* p, int n) {
    int i = blockIdx.x * blockDim.x + threadIdx.x;
    if (i < n) p[i] = 0.f;
}

__global__ void hist_kernel(const int* __restrict__ rows, int* __restrict__ cnt) {
    int e = blockIdx.x * blockDim.x + threadIdx.x;
    if (e < N_EDGES) atomicAdd(&cnt[rows[e]], 1);
}

__global__ __launch_bounds__(256) void scan1_kernel(const int* __restrict__ cnt,
                                                    int* __restrict__ off,
                                                    int* __restrict__ bsum) {
    __shared__ int sm[256];
    int b = blockIdx.x, t = threadIdx.x;
    int base = b * SCAN_CHUNK + t * 4;
    int v[4];
    int tsum = 0;
#pragma unroll
    for (int j = 0; j < 4; ++j) {
        v[j] = (base + j < N_NODES) ? cnt[base + j] : 0;
        tsum += v[j];
    }
    int val = tsum;
    sm[t] = val;
    __syncthreads();
    for (int d = 1; d < 256; d <<= 1) {
        int x = (t >= d) ? sm[t - d] : 0;
        __syncthreads();
        val += x;
        sm[t] = val;
        __syncthreads();
    }
    int run = val - tsum;
#pragma unroll
    for (int j = 0; j < 4; ++j) {
        if (base + j < N_NODES) off[base + j] = run;
        run += v[j];
    }
    if (t == 255) bsum[b] = val;
}

__global__ __launch_bounds__(128) void scan2_kernel(int* __restrict__ bsum) {
    __shared__ int sm[128];
    int t = threadIdx.x;
    int v = (t < NBLK_SCAN) ? bsum[t] : 0;
    int val = v;
    sm[t] = val;
    __syncthreads();
    for (int d = 1; d < 128; d <<= 1) {
        int x = (t >= d) ? sm[t - d] : 0;
        __syncthreads();
        val += x;
        sm[t] = val;
        __syncthreads();
    }
    if (t < NBLK_SCAN) bsum[t] = val - v;
}

__global__ __launch_bounds__(256) void scan3_kernel(int* __restrict__ off,
                                                    const int* __restrict__ bsum) {
    int b = blockIdx.x, t = threadIdx.x;
    int add = bsum[b];
    int base = b * SCAN_CHUNK + t * 4;
#pragma unroll
    for (int j = 0; j < 4; ++j)
        if (base + j < N_NODES) off[base + j] += add;
    if (b == 0 && t == 0) off[N_NODES] = N_EDGES;
}

// wc layout: [0..74] W1S[j*5+i]=W1[(8+i)*15+j] | [75..149] W2T[j*15+i]=W2[i*5+j]
//            [150..154] b2 | [160..279] W1F[j*8+i]=W1[i*15+j] | [280..294] b1
__global__ void wprep_kernel(const float* __restrict__ W1, const float* __restrict__ b1,
                             const float* __restrict__ W2, const float* __restrict__ b2,
                             float* __restrict__ wc) {
    int t = threadIdx.x;
    for (int idx = t; idx < 75; idx += 256) { int j = idx / 5, i = idx % 5; wc[idx] = W1[(8 + i) * 15 + j]; }
    for (int idx = t; idx < 75; idx += 256) { int j = idx / 15, i = idx % 15; wc[75 + idx] = W2[i * 5 + j]; }
    for (int idx = t; idx < 5; idx += 256) wc[150 + idx] = b2[idx];
    for (int idx = t; idx < 120; idx += 256) { int j = idx / 8, i = idx % 8; wc[160 + idx] = W1[i * 15 + j]; }
    for (int idx = t; idx < 15; idx += 256) wc[280 + idx] = b1[idx];
}

union RecPack { __half2 h2[8]; uint4 u4[2]; };
union U4H { uint4 u; __half2 h[4]; };

// Fused build: sequential edge reads, hoisted c1 compute, scattered CSR write.
__global__ __launch_bounds__(256) void scatter_build2(
    const int* __restrict__ rows, const int* __restrict__ esrc,
    const float* __restrict__ avals, const float* __restrict__ efeat,
    const int* __restrict__ off, int* __restrict__ cur,
    const float* __restrict__ wc,
    uint4* __restrict__ c1h, int2* __restrict__ sv, int* __restrict__ rowsg) {
    int e = blockIdx.x * blockDim.x + threadIdx.x;
    if (e >= N_EDGES) return;
    int r = rows[e];
    int p = off[r] + atomicAdd(&cur[r], 1);
    const float4* fp = (const float4*)(efeat + (size_t)e * 8);
    float4 f0 = fp[0], f1 = fp[1];
    const float* W1F = wc + 160;
    const float* B1 = wc + 280;
    float c[15];
#pragma unroll
    for (int j = 0; j < 15; ++j) {
        float a = B1[j];
        a += f0.x * W1F[j * 8 + 0] + f0.y * W1F[j * 8 + 1] + f0.z * W1F[j * 8 + 2] + f0.w * W1F[j * 8 + 3];
        a += f1.x * W1F[j * 8 + 4] + f1.y * W1F[j * 8 + 5] + f1.z * W1F[j * 8 + 6] + f1.w * W1F[j * 8 + 7];
        c[j] = a;
    }
    RecPack rp;
#pragma unroll
    for (int j = 0; j < 7; ++j) rp.h2[j] = __floats2half2_rn(c[2 * j], c[2 * j + 1]);
    rp.h2[7] = __floats2half2_rn(c[14], 0.f);
    c1h[2 * p] = rp.u4[0];
    c1h[2 * p + 1] = rp.u4[1];
    sv[p] = make_int2(esrc[e], __float_as_int(avals[e]));
    rowsg[p] = r;
}

__global__ void init_state8_kernel(const float* __restrict__ state_init,
                                   const float* __restrict__ old_init,
                                   float* __restrict__ buf0,
                                   int* __restrict__ flags) {
    int n = blockIdx.x * blockDim.x + threadIdx.x;
    if (n >= N_NODES) return;
    float ss = 0.f;
    float s[5];
#pragma unroll
    for (int j = 0; j < 5; ++j) {
        s[j] = state_init[n * 5 + j];
        float d = s[j] - old_init[n * 5 + j];
        ss += d * d;
    }
    ((float4*)(buf0 + (size_t)n * 8))[0] = make_float4(s[0], s[1], s[2], s[3]);
    ((float4*)(buf0 + (size_t)n * 8))[1] = make_float4(s[4], 0.f, 0.f, 0.f);
    int pred = sqrtf(ss + 1e-11f) > THRESH;
    unsigned long long m = __ballot(pred);
    if ((threadIdx.x & 63) == 0 && m) atomicOr(&flags[0], 1);
}

// ---- hot kernel: persistent waves, 320 slots/wave, 2-level pipeline,
//      ballot-based wave segmented scan, in-register carry across groups ----
__global__ __launch_bounds__(256) void edge_pipe_kernel(
    const int* __restrict__ rowsg, const uint4* __restrict__ c1h,
    const int2* __restrict__ sv,
    const float* __restrict__ sprev, float* __restrict__ snext,
    const float* __restrict__ wc, const int* __restrict__ flag_cur) {
    if (*flag_cur == 0) return;
    int gtid = blockIdx.x * 256 + threadIdx.x;
    int wid = gtid >> 6;
    int lane = threadIdx.x & 63;
    if (wid >= WAVES_TOTAL) return;
    int base = wid * SLOTS_W;

    int head_prev = (wid > 0) ? rowsg[base - 1] : -2;
    int tail_next = (wid < WAVES_TOTAL - 1) ? rowsg[base + SLOTS_W] : -2;

    const float* W1S = wc;        // [15][5]
    const float* W2T = wc + 75;   // [5][15]
    const float* B2  = wc + 150;

    int carry_row = -1;
    bool carry_head = false;
    float cv0 = 0, cv1 = 0, cv2 = 0, cv3 = 0, cv4 = 0;

    // ---- pipeline preload ----
    int p0 = base + lane;
    int2 s0m = sv[p0];            int r0v = rowsg[p0];
    int2 s1m = sv[p0 + 64];       int r1v = rowsg[p0 + 64];
    float4 g0a = ((const float4*)(sprev + (size_t)s0m.x * 8))[0];
    float  g0b = sprev[(size_t)s0m.x * 8 + 4];
    uint4 c0a = c1h[2 * p0], c0b = c1h[2 * p0 + 1];

    for (int k = 0; k < GROUPS; ++k) {
        // stage: meta for group k+2
        int2 s2m; int r2v;
        if (k + 2 < GROUPS) {
            int p2 = base + (k + 2) * 64 + lane;
            s2m = sv[p2]; r2v = rowsg[p2];
        }
        // stage: gather + c1h for group k+1
        float4 g1a; float g1b; uint4 c1a, c1b;
        if (k + 1 < GROUPS) {
            int p1 = base + (k + 1) * 64 + lane;
            g1a = ((const float4*)(sprev + (size_t)s1m.x * 8))[0];
            g1b = sprev[(size_t)s1m.x * 8 + 4];
            c1a = c1h[2 * p1]; c1b = c1h[2 * p1 + 1];
        }
        // ---- compute group k ----
        int r = r0v;
        float av = __int_as_float(s0m.y);
        U4H ua, ub;
        ua.u = c0a; ub.u = c0b;
        float c1[15];
#pragma unroll
        for (int j = 0; j < 4; ++j) {
            float2 f = __half22float2(ua.h[j]);
            c1[2 * j] = f.x; c1[2 * j + 1] = f.y;
        }
#pragma unroll
        for (int j = 0; j < 3; ++j) {
            float2 f = __half22float2(ub.h[j]);
            c1[8 + 2 * j] = f.x; c1[9 + 2 * j] = f.y;
        }
        c1[14] = __half22float2(ub.h[3]).x;
        float h1[15];
#pragma unroll
        for (int j = 0; j < 15; ++j) {
            float a = c1[j];
            a += g0a.x * W1S[j * 5 + 0];
            a += g0a.y * W1S[j * 5 + 1];
            a += g0a.z * W1S[j * 5 + 2];
            a += g0a.w * W1S[j * 5 + 3];
            a += g0b  * W1S[j * 5 + 4];
            h1[j] = fast_tanh(a);
        }
        float v0, v1, v2, v3, v4;
        {
            float o[5];
#pragma unroll
            for (int j = 0; j < 5; ++j) {
                float a = B2[j];
#pragma unroll
                for (int i = 0; i < 15; ++i) a += h1[i] * W2T[j * 15 + i];
                o[j] = fast_tanh(a) * av;
            }
            v0 = o[0]; v1 = o[1]; v2 = o[2]; v3 = o[3]; v4 = o[4];
        }
        // ---- ballot-based segmented inclusive scan (rows non-decreasing) ----
        int rprev = __shfl_up(r, 1, 64);
        bool head = (lane == 0) || (rprev != r);
        unsigned long long hm = __ballot(head);
        unsigned long long below = hm & (0xFFFFFFFFFFFFFFFFULL >> (63 - lane));
        int segstart = 63 - __clzll(below);
#pragma unroll
        for (int d = 1; d < 64; d <<= 1) {
            float t0 = __shfl_up(v0, d, 64);
            float t1 = __shfl_up(v1, d, 64);
            float t2 = __shfl_up(v2, d, 64);
            float t3 = __shfl_up(v3, d, 64);
            float t4 = __shfl_up(v4, d, 64);
            if (lane - d >= segstart) { v0 += t0; v1 += t1; v2 += t2; v3 += t3; v4 += t4; }
        }
        bool next_head = (lane < 63) && ((hm >> (lane + 1)) & 1ULL);
        bool is_tail = (lane == 63) || next_head;
        int r_next_first = (k + 1 < GROUPS) ? __shfl(r1v, 0, 64) : -3;

        float w0 = v0, w1 = v1, w2 = v2, w3 = v3, w4 = v4;
        if (is_tail && r == carry_row) { w0 += cv0; w1 += cv1; w2 += cv2; w3 += cv3; w4 += cv4; }
        bool rh = (r == carry_row && carry_head) || (k == 0 && head_prev == r);
        bool cont = is_tail && (lane == 63) && (k + 1 < GROUPS) && (r == r_next_first);
        if (is_tail && !cont) {
            bool wec = (lane == 63) && (k == GROUPS - 1) && (r == tail_next);
            float* dst = snext + (size_t)r * 8;
            if (rh || wec) {
                atomicAdd(dst + 0, w0);
                atomicAdd(dst + 1, w1);
                atomicAdd(dst + 2, w2);
                atomicAdd(dst + 3, w3);
                atomicAdd(dst + 4, w4);
            } else {
                ((float4*)dst)[0] = make_float4(w0, w1, w2, w3);
                dst[4] = w4;
            }
        }
        // carry from lane 63
        int cont63 = __shfl((int)cont, 63, 64);
        int cr63 = __shfl(r, 63, 64);
        int ch63 = __shfl((int)rh, 63, 64);
        float nc0 = __shfl(w0, 63, 64);
        float nc1 = __shfl(w1, 63, 64);
        float nc2 = __shfl(w2, 63, 64);
        float nc3 = __shfl(w3, 63, 64);
        float nc4 = __shfl(w4, 63, 64);
        carry_row = cont63 ? cr63 : -1;
        carry_head = cont63 && ch63;
        cv0 = nc0; cv1 = nc1; cv2 = nc2; cv3 = nc3; cv4 = nc4;
        // rotate pipeline
        s0m = s1m; r0v = r1v; g0a = g1a; g0b = g1b; c0a = c1a; c0b = c1b;
        s1m = s2m; r1v = r2v;
    }
}

// Per-node: convergence flag, kcnt, inactive-copy; zeroes sp for next iter.
__global__ void node_pass_kernel(float* __restrict__ sp, float* __restrict__ sn,
                                 const int* __restrict__ flag_cur,
                                 int* __restrict__ flag_next,
                                 int* __restrict__ kcnt) {
    int n = blockIdx.x * blockDim.x + threadIdx.x;
    if (n >= N_NODES) return;
    bool active = (*flag_cur != 0);
    float4 o0 = ((const float4*)(sp + (size_t)n * 8))[0];
    float o4 = sp[(size_t)n * 8 + 4];
    int pred = 0;
    if (active) {
        if (n == 0) *kcnt += 1;
        float4 s0 = ((const float4*)(sn + (size_t)n * 8))[0];
        float s4 = sn[(size_t)n * 8 + 4];
        float d0 = s0.x - o0.x, d1 = s0.y - o0.y, d2 = s0.z - o0.z;
        float d3 = s0.w - o0.w, d4 = s4 - o4;
        float ss = d0 * d0 + d1 * d1 + d2 * d2 + d3 * d3 + d4 * d4;
        pred = sqrtf(ss + 1e-11f) > THRESH;
    } else {
        ((float4*)(sn + (size_t)n * 8))[0] = o0;
        sn[(size_t)n * 8 + 4] = o4;
    }
    ((float4*)(sp + (size_t)n * 8))[0] = make_float4(0.f, 0.f, 0.f, 0.f);
    sp[(size_t)n * 8 + 4] = 0.f;
    unsigned long long m = __ballot(pred);
    if ((threadIdx.x & 63) == 0 && m) atomicOr(flag_next, 1);
}

__global__ void final8_kernel(const float* __restrict__ state,
                              const float* __restrict__ W3, const float* __restrict__ b3,
                              const float* __restrict__ W4, const float* __restrict__ b4,
                              const int* __restrict__ kcnt,
                              float* __restrict__ out) {
    int n = blockIdx.x * blockDim.x + threadIdx.x;
    if (n == 0) out[(size_t)N_NODES * 7] = (float)(*kcnt);
    if (n >= N_NODES) return;
    float st[5];
    float4 s0 = ((const float4*)(state + (size_t)n * 8))[0];
    st[0] = s0.x; st[1] = s0.y; st[2] = s0.z; st[3] = s0.w;
    st[4] = state[(size_t)n * 8 + 4];
    float o1[10];
#pragma unroll
    for (int j = 0; j < 10; ++j) {
        float a = b3[j];
#pragma unroll
        for (int i = 0; i < 5; ++i) a += st[i] * W3[i * 10 + j];
        o1[j] = tanhf(a);
    }
    float z[7];
    float m = -1e30f;
#pragma unroll
    for (int j = 0; j < 7; ++j) {
        float a = b4[j];
#pragma unroll
        for (int i = 0; i < 10; ++i) a += o1[i] * W4[i * 7 + j];
        z[j] = a;
        m = fmaxf(m, a);
    }
    float s = 0.f;
#pragma unroll
    for (int j = 0; j < 7; ++j) { z[j] = expf(z[j] - m); s += z[j]; }
    float inv = 1.f / s;
#pragma unroll
    for (int j = 0; j < 7; ++j) out[(size_t)n * 7 + j] = z[j] * inv;
}

extern "C" void kernel_launch(void* const* d_in, const int* in_sizes, int n_in,
                              void* d_out, int out_size, void* d_ws, size_t ws_size,
                              hipStream_t stream) {
    const float* edge_feat  = (const float*)d_in[0];
    const int*   edge_src   = (const int*)d_in[1];
    const int*   arc_rows   = (const int*)d_in[2];
    const float* arc_vals   = (const float*)d_in[3];
    const float* state_init = (const float*)d_in[4];
    const float* old_init   = (const float*)d_in[5];
    const float* W1 = (const float*)d_in[6];
    const float* b1 = (const float*)d_in[7];
    const float* W2 = (const float*)d_in[8];
    const float* b2 = (const float*)d_in[9];
    const float* W3 = (const float*)d_in[10];
    const float* b3 = (const float*)d_in[11];
    const float* W4 = (const float*)d_in[12];
    const float* b4 = (const float*)d_in[13];

    char* ws = (char*)d_ws;
    int*   off   = (int*)(ws + 0);
    int*   cnt   = (int*)(ws + 400128);
    int*   flags = (int*)(ws + 800128);
    int*   kcnt  = flags + 51;
    float* wc    = (float*)(ws + 800384);
    float* buf0  = (float*)(ws + 801664);
    float* buf1  = (float*)(ws + 4001664);
    int*   rowsg = (int*)(ws + 7201664);
    int2*  sv    = (int2*)(ws + 13601664);
    uint4* c1h   = (uint4*)(ws + 26401664);
    int*   bsum  = (int*)(ws + 26401664);  // scratch; dead before c1h written

    int nb = (N_NODES + 255) / 256;
    int eb = NB_EDGE;

    // ---- one-time CSR + record build ----
    hipLaunchKernelGGL(zero_ints, dim3(nb), dim3(256), 0, stream, cnt, N_NODES);
    hipLaunchKernelGGL(zero_ints, dim3(1), dim3(64), 0, stream, flags, 52);
    hipLaunchKernelGGL(hist_kernel, dim3(eb), dim3(256), 0, stream, arc_rows, cnt);
    hipLaunchKernelGGL(scan1_kernel, dim3(NBLK_SCAN), dim3(256), 0, stream, cnt, off, bsum);
    hipLaunchKernelGGL(scan2_kernel, dim3(1), dim3(128), 0, stream, bsum);
    hipLaunchKernelGGL(scan3_kernel, dim3(NBLK_SCAN), dim3(256), 0, stream, off, bsum);
    hipLaunchKernelGGL(zero_ints, dim3(nb), dim3(256), 0, stream, cnt, N_NODES);
    hipLaunchKernelGGL(wprep_kernel, dim3(1), dim3(256), 0, stream, W1, b1, W2, b2, wc);
    hipLaunchKernelGGL(scatter_build2, dim3(eb), dim3(256), 0, stream,
                       arc_rows, edge_src, arc_vals, edge_feat, off, cnt, wc, c1h, sv, rowsg);
    hipLaunchKernelGGL(init_state8_kernel, dim3(nb), dim3(256), 0, stream,
                       state_init, old_init, buf0, flags);
    hipLaunchKernelGGL(zero_floats, dim3((N_NODES * 8 + 255) / 256), dim3(256), 0, stream,
                       buf1, N_NODES * 8);

    // ---- 50 iterations: edge_pipe (accumulate into pre-zeroed sn) + node_pass ----
    for (int it = 0; it < MAX_ITER; ++it) {
        float* sp = (it & 1) ? buf1 : buf0;
        float* sn = (it & 1) ? buf0 : buf1;
        hipLaunchKernelGGL(edge_pipe_kernel, dim3(BLK_PIPE), dim3(256), 0, stream,
                           rowsg, c1h, sv, sp, sn, wc, flags + it);
        hipLaunchKernelGGL(node_pass_kernel, dim3(nb), dim3(256), 0, stream,
                           sp, sn, flags + it, flags + it + 1, kcnt);
    }

    hipLaunchKernelGGL(final8_kernel, dim3(nb), dim3(256), 0, stream,
                       buf0, W3, b3, W4, b4, kcnt, (float*)d_out);
}